// Round 9
// baseline (497.778 us; speedup 1.0000x reference)
//
#include <hip/hip_runtime.h>
#include <math.h>

#define N_NODES 100000
#define N_EDGES 3200000
#define KH 48            // K*H active channels
#define FDIM 64          // padded feature row stride (128 B, line-aligned)
#define NH 16            // H
#define BN_EPS 1e-5f
#define NBUCK 196        // ceil(100000/512) buckets of 512 nodes
#define BSHIFT 9
#define BMASK 511
#define EPB 16384        // edges per block in bucket scatter
#define NBLK1 196        // ceil(N_EDGES/EPB)
#define CAP 18432        // fixed bucket capacity: mean 16327 + 16 sigma
#define FIX 16777216.0f  // 2^24 fixed point for degree sums

typedef unsigned long long u64;
typedef unsigned int u32;
typedef unsigned short u16;

__device__ __forceinline__ u16 f2bf(float f) {
  u32 b = __float_as_uint(f);
  b += 0x7FFFu + ((b >> 16) & 1u);   // RNE
  return (u16)(b >> 16);
}
__device__ __forceinline__ float bf2f(u32 s) {
  return __uint_as_float(s << 16);
}
__device__ __forceinline__ u32 rfl(u32 v) {
  return (u32)__builtin_amdgcn_readfirstlane((int)v);
}

// ---------------- K1: scatter edges into FIXED-CAPACITY buckets -------------
__global__ __launch_bounds__(1024) void bucket_scatter_kernel(
    const int* __restrict__ row, const int* __restrict__ col,
    const float* __restrict__ ea, u32* __restrict__ gcur,
    int2* __restrict__ bucketed) {
  __shared__ u32 bins[NBUCK];
  __shared__ u32 base[NBUCK];
  __shared__ u16 rnk[EPB];
  for (int t = threadIdx.x; t < NBUCK; t += 1024) bins[t] = 0;
  __syncthreads();
  int eb = blockIdx.x * EPB;
  for (int it = 0; it < EPB / 1024; ++it) {
    int i = it * 1024 + threadIdx.x;
    int e = eb + i;
    if (e < N_EDGES) rnk[i] = (u16)atomicAdd(&bins[col[e] >> BSHIFT], 1u);
  }
  __syncthreads();
  for (int t = threadIdx.x; t < NBUCK; t += 1024) {
    u32 c = bins[t];
    if (c) base[t] = (u32)t * CAP + atomicAdd(&gcur[t * 8], c);
  }
  __syncthreads();
  for (int it = 0; it < EPB / 1024; ++it) {
    int i = it * 1024 + threadIdx.x;
    int e = eb + i;
    if (e < N_EDGES) {
      int c = col[e];
      int bkt = c >> BSHIFT, cl = c & BMASK;
      u32 pos = base[bkt] + (u32)rnk[i];
      bucketed[pos] = make_int2((cl << 17) | row[e], __float_as_int(ea[e]));
    }
  }
}

// ---------------- P2: FUSED per-bucket offs/dinv/zx + csr fill --------------
__global__ __launch_bounds__(1024) void node_offs_csr_kernel(
    const int2* __restrict__ bucketed, const u32* __restrict__ gcur,
    const float* __restrict__ x,
    int* __restrict__ offs, float* __restrict__ dinv, u16* __restrict__ zx,
    u32* __restrict__ csr) {
  __shared__ u32 cnt[512];
  __shared__ u32 degf[512];
  __shared__ u32 cur[512];
  __shared__ u32 red[256];
  __shared__ u32 shmeta[2];   // [0]=bstart, [1]=fill
  int t = threadIdx.x;
  int b = blockIdx.x;
  if (t < 512) { cnt[t] = 0; degf[t] = 0; }
  if (t < 256) red[t] = (t < b) ? gcur[t * 8] : 0;   // NBUCK<256
  __syncthreads();
  for (int d = 128; d; d >>= 1) {
    if (t < d) red[t] += red[t + d];
    __syncthreads();
  }
  if (t == 0) { shmeta[0] = red[0]; shmeta[1] = gcur[b * 8]; }
  __syncthreads();
  u32 bst = shmeta[0], fill = shmeta[1];
  u32 s_pad = (u32)b * CAP;
  for (u32 i = t; i < fill; i += 1024) {
    int2 v = bucketed[s_pad + i];
    int cl = (v.x >> 17) & BMASK;
    atomicAdd(&cnt[cl], 1u);
    atomicAdd(&degf[cl], (u32)(__int_as_float(v.y) * FIX));
  }
  __syncthreads();
  u32 v0 = (t < 512) ? cnt[t] : 0;
  for (int d = 1; d < 512; d <<= 1) {
    u32 u = (t < 512 && t >= d) ? cnt[t - d] : 0;
    __syncthreads();
    if (t < 512) cnt[t] += u;
    __syncthreads();
  }
  int n = b * 512 + t;
  if (t < 512) {
    if (n < N_NODES) {
      u32 off0 = bst + cnt[t] - v0;   // exclusive, compact
      offs[n] = (int)off0;
      cur[t] = off0;
      float dg = (float)degf[t] * (1.0f / FIX);
      float dv = dg > 0.f ? rsqrtf(fmaxf(dg, 1e-12f)) : 0.f;
      dinv[n] = dv;
      zx[n] = f2bf(x[n] * dv);
    } else {
      cur[t] = 0;
    }
  }
  if (b == 0 && t == 0) offs[N_NODES] = N_EDGES;
  __syncthreads();
  for (u32 i = t; i < fill; i += 1024) {
    int2 v = bucketed[s_pad + i];
    int cl = (v.x >> 17) & BMASK;
    u32 r = (u32)(v.x & 0x1FFFF);
    u16 w = f2bf(__int_as_float(v.y));   // ea >= 0 -> sign bit 0, w < 0x8000
    u32 pos = atomicAdd(&cur[cl], 1u);
    csr[pos] = (r << 15) | (u32)w;
  }
}

// ---------------- layer-1: scalar prop + epilogue + transform (merged) ------
// 32-lane groups: one (csr,zx-gather) pair per lane (degree ~32 -> 1 iter).
__global__ __launch_bounds__(256) void sprop_mid_kernel(
    const u32* __restrict__ csr, const int* __restrict__ offs,
    const u16* __restrict__ zx, const float* __restrict__ dinv,
    const float* __restrict__ x,
    const float* __restrict__ w1i, const float* __restrict__ w1r,
    const float* __restrict__ b1, const float* __restrict__ w1,
    u16* __restrict__ tout) {
  int t = blockIdx.x * 256 + threadIdx.x;
  int n = t >> 5;            // node per 32-lane group
  int c32 = t & 31;
  int c = c32 & 15;          // channel
  float a = 0.f;
  int s = offs[n], e = offs[n + 1];
  for (int i = s + c32; i < e; i += 32) {
    u32 ee = csr[i];
    a += bf2f(ee & 0x7FFFu) * bf2f((u32)zx[ee >> 15]);
  }
#pragma unroll
  for (int o = 16; o; o >>= 1) a += __shfl_xor(a, o, 64);
  float dn = dinv[n];
  float sn = a * dn;
  float xn = x[n];
  int base = (threadIdx.x & 63) & 32;   // group base within wave
#pragma unroll
  for (int k = 0; k < 3; ++k) {
    float u = fmaxf(sn * w1i[k * 16 + c] + xn * w1r[k * 16 + c] + b1[k * 16 + c], 0.f);
    float tf = 0.f;
#pragma unroll
    for (int f = 0; f < 16; ++f) tf += __shfl(u, base + f, 64) * w1[k * 256 + f * 16 + c];
    if (c32 < 16) tout[(size_t)n * FDIM + k * 16 + c] = f2bf(tf * dn);
  }
}

// ---------------- conv1 propagate, all 3 stacks combined --------------------
// wave per node, lane = channel, 48 active; rows 128 B line-aligned.
// csr values pulled through the SCALAR path (readfirstlane -> SALU unpack,
// SGPR-based gather addresses). [R4 form — proven 61.4 us, at the random-
// line fetch BW ceiling: 163 MB/dispatch at ~2.8 TB/s = 95% of floor.]
__global__ __launch_bounds__(256) void conv1_prop_kernel(
    const u16* __restrict__ tin, u16* __restrict__ tout, float* __restrict__ hbuf,
    const u32* __restrict__ csr, const int* __restrict__ offs,
    const float* __restrict__ dinv, const float* __restrict__ x,
    const float* __restrict__ w1r, const float* __restrict__ b1,
    const float* __restrict__ w1, int do_t) {
  int lane = threadIdx.x & 63;
  int wid = (blockIdx.x * blockDim.x + threadIdx.x) >> 6;
  int nw = (gridDim.x * blockDim.x) >> 6;
  int c = lane;
  bool act = c < KH;
  float rb = act ? w1r[c] : 0.f;
  float bb = act ? b1[c] : 0.f;
  float wreg[16];
  if (do_t) {
    int k = c >> 4, o = c & 15;
    if (act) {
#pragma unroll
      for (int f = 0; f < 16; ++f) wreg[f] = w1[k * 256 + f * 16 + o];
    } else {
#pragma unroll
      for (int f = 0; f < 16; ++f) wreg[f] = 0.f;
    }
  }
  for (int n = wid; n < N_NODES; n += nw) {
    int nu = __builtin_amdgcn_readfirstlane(n);
    int s = __builtin_amdgcn_readfirstlane(offs[nu]);
    int e = __builtin_amdgcn_readfirstlane(offs[nu + 1]);
    float acc = 0.f;
    int i = s;
    for (; i + 16 <= e; i += 16) {
      u32 e0 = rfl(csr[i]);
      u32 e1 = rfl(csr[i + 1]);
      u32 e2 = rfl(csr[i + 2]);
      u32 e3 = rfl(csr[i + 3]);
      u32 e4 = rfl(csr[i + 4]);
      u32 e5 = rfl(csr[i + 5]);
      u32 e6 = rfl(csr[i + 6]);
      u32 e7 = rfl(csr[i + 7]);
      u32 e8 = rfl(csr[i + 8]);
      u32 e9 = rfl(csr[i + 9]);
      u32 ea0 = rfl(csr[i + 10]);
      u32 eb0 = rfl(csr[i + 11]);
      u32 ec0 = rfl(csr[i + 12]);
      u32 ed0 = rfl(csr[i + 13]);
      u32 ee0 = rfl(csr[i + 14]);
      u32 ef0 = rfl(csr[i + 15]);
      float v0 = bf2f((u32)tin[(e0 >> 15) * FDIM + c]);
      float v1 = bf2f((u32)tin[(e1 >> 15) * FDIM + c]);
      float v2 = bf2f((u32)tin[(e2 >> 15) * FDIM + c]);
      float v3 = bf2f((u32)tin[(e3 >> 15) * FDIM + c]);
      float v4 = bf2f((u32)tin[(e4 >> 15) * FDIM + c]);
      float v5 = bf2f((u32)tin[(e5 >> 15) * FDIM + c]);
      float v6 = bf2f((u32)tin[(e6 >> 15) * FDIM + c]);
      float v7 = bf2f((u32)tin[(e7 >> 15) * FDIM + c]);
      float v8 = bf2f((u32)tin[(e8 >> 15) * FDIM + c]);
      float v9 = bf2f((u32)tin[(e9 >> 15) * FDIM + c]);
      float va = bf2f((u32)tin[(ea0 >> 15) * FDIM + c]);
      float vb = bf2f((u32)tin[(eb0 >> 15) * FDIM + c]);
      float vc = bf2f((u32)tin[(ec0 >> 15) * FDIM + c]);
      float vd = bf2f((u32)tin[(ed0 >> 15) * FDIM + c]);
      float ve = bf2f((u32)tin[(ee0 >> 15) * FDIM + c]);
      float vf = bf2f((u32)tin[(ef0 >> 15) * FDIM + c]);
      acc += bf2f(e0 & 0x7FFFu) * v0 + bf2f(e1 & 0x7FFFu) * v1 +
             bf2f(e2 & 0x7FFFu) * v2 + bf2f(e3 & 0x7FFFu) * v3 +
             bf2f(e4 & 0x7FFFu) * v4 + bf2f(e5 & 0x7FFFu) * v5 +
             bf2f(e6 & 0x7FFFu) * v6 + bf2f(e7 & 0x7FFFu) * v7 +
             bf2f(e8 & 0x7FFFu) * v8 + bf2f(e9 & 0x7FFFu) * v9 +
             bf2f(ea0 & 0x7FFFu) * va + bf2f(eb0 & 0x7FFFu) * vb +
             bf2f(ec0 & 0x7FFFu) * vc + bf2f(ed0 & 0x7FFFu) * vd +
             bf2f(ee0 & 0x7FFFu) * ve + bf2f(ef0 & 0x7FFFu) * vf;
    }
    for (; i + 4 <= e; i += 4) {
      u32 e0 = rfl(csr[i]);
      u32 e1 = rfl(csr[i + 1]);
      u32 e2 = rfl(csr[i + 2]);
      u32 e3 = rfl(csr[i + 3]);
      float v0 = bf2f((u32)tin[(e0 >> 15) * FDIM + c]);
      float v1 = bf2f((u32)tin[(e1 >> 15) * FDIM + c]);
      float v2 = bf2f((u32)tin[(e2 >> 15) * FDIM + c]);
      float v3 = bf2f((u32)tin[(e3 >> 15) * FDIM + c]);
      acc += bf2f(e0 & 0x7FFFu) * v0 + bf2f(e1 & 0x7FFFu) * v1 +
             bf2f(e2 & 0x7FFFu) * v2 + bf2f(e3 & 0x7FFFu) * v3;
    }
    for (; i < e; ++i) {
      u32 ee = rfl(csr[i]);
      acc += bf2f(ee & 0x7FFFu) * bf2f((u32)tin[(ee >> 15) * FDIM + c]);
    }
    float dn = dinv[nu];
    float u = fmaxf(acc * dn + x[nu] * rb + bb, 0.f);
    if (do_t) {
      float tf = 0.f;
      int base = c & 48;
#pragma unroll
      for (int f = 0; f < 16; ++f) tf += __shfl(u, base + f, 64) * wreg[f];
      if (act) tout[(size_t)nu * FDIM + c] = f2bf(tf * dn);
    } else {
      float m1v = __shfl(u, lane + 16, 64);
      float m2v = __shfl(u, lane + 32, 64);
      if (lane < NH) hbuf[(size_t)nu * NH + lane] = (u + m1v + m2v) * (1.f / 3.f);
    }
  }
}

// ---------------- BN stats over hbuf [N,16] ---------------------------------
__global__ __launch_bounds__(256) void bn_stats_kernel(
    const float* __restrict__ h, double* __restrict__ stats) {
  __shared__ float ssum[NH], ssq[NH];
  int tid = threadIdx.x;
  if (tid < NH) { ssum[tid] = 0.f; ssq[tid] = 0.f; }
  __syncthreads();
  int n = blockIdx.x * blockDim.x + tid;
  bool valid = n < N_NODES;
  const float4* p = (const float4*)(h + (size_t)(valid ? n : 0) * NH);
  float hv[NH];
#pragma unroll
  for (int q = 0; q < 4; ++q) {
    float4 v = valid ? p[q] : make_float4(0.f, 0.f, 0.f, 0.f);
    hv[q * 4 + 0] = v.x; hv[q * 4 + 1] = v.y; hv[q * 4 + 2] = v.z; hv[q * 4 + 3] = v.w;
  }
#pragma unroll
  for (int f = 0; f < NH; ++f) {
    float s = hv[f], q = hv[f] * hv[f];
    for (int o = 32; o; o >>= 1) { s += __shfl_xor(s, o, 64); q += __shfl_xor(q, o, 64); }
    if ((tid & 63) == 0) { atomicAdd(&ssum[f], s); atomicAdd(&ssq[f], q); }
  }
  __syncthreads();
  if (tid < NH) {
    atomicAdd(&stats[tid], (double)ssum[tid]);
    atomicAdd(&stats[NH + tid], (double)ssq[tid]);
  }
}

__global__ __launch_bounds__(64) void bn_final_kernel(
    const double* __restrict__ stats, const float* __restrict__ g,
    const float* __restrict__ b, float* __restrict__ sc, float* __restrict__ sh) {
  int f = threadIdx.x;
  if (f < NH) {
    double mu = stats[f] / (double)N_NODES;
    double var = stats[NH + f] / (double)N_NODES - mu * mu;
    float scale = g[f] * (float)(1.0 / sqrt(var + (double)BN_EPS));
    sc[f] = scale;
    sh[f] = b[f] - (float)mu * scale;
  }
}

// ---------------- conv2 init: BN-apply + relu + init/root dots --------------
__global__ __launch_bounds__(256) void conv2_init_kernel(
    const float* __restrict__ h, const float* __restrict__ sc, const float* __restrict__ sh,
    const float* __restrict__ dinv,
    const float* __restrict__ w2i, const float* __restrict__ w2r, const float* __restrict__ b2,
    float* __restrict__ P, float* __restrict__ R) {
  int n = blockIdx.x * blockDim.x + threadIdx.x;
  if (n >= N_NODES) return;
  float u[NH];
#pragma unroll
  for (int f = 0; f < NH; ++f) u[f] = fmaxf(h[(size_t)n * NH + f] * sc[f] + sh[f], 0.f);
  float dn = dinv[n];
#pragma unroll
  for (int k = 0; k < 3; ++k) {
    float r = b2[k], o = 0.f;
#pragma unroll
    for (int f = 0; f < NH; ++f) {
      r += u[f] * w2r[k * NH + f];
      o += u[f] * w2i[k * NH + f];
    }
    R[n * 4 + k] = r;
    P[n * 4 + k] = o * dn;
  }
  R[n * 4 + 3] = 0.f;
  P[n * 4 + 3] = 0.f;
}

// ---------------- conv2 propagate: 32-lane groups, packed CSR ---------------
// degree ~32 -> each lane does ~1 (csr,gather) pair; no serial re-issue.
__global__ __launch_bounds__(256) void conv2_prop_kernel(
    const float* __restrict__ in4, float* __restrict__ out4, float* __restrict__ y,
    const u32* __restrict__ csr, const int* __restrict__ offs,
    const float* __restrict__ dinv,
    const float* __restrict__ R, const float* __restrict__ w2,
    int scale_w2, int final_out) {
  int t = blockIdx.x * 256 + threadIdx.x;
  int n = t >> 5, sub = t & 31;
  float m0 = 1.f, m1 = 1.f, m2 = 1.f;
  if (scale_w2) { m0 = w2[0]; m1 = w2[1]; m2 = w2[2]; }
  int s = offs[n], e = offs[n + 1];
  float a0 = 0.f, a1 = 0.f, a2 = 0.f;
  for (int i = s + sub; i < e; i += 32) {
    u32 ee = csr[i];
    float w = bf2f(ee & 0x7FFFu);
    const float4 v = *(const float4*)(in4 + (size_t)(ee >> 15) * 4);
    a0 += w * v.x;
    a1 += w * v.y;
    a2 += w * v.z;
  }
#pragma unroll
  for (int o = 16; o; o >>= 1) {
    a0 += __shfl_xor(a0, o, 64);
    a1 += __shfl_xor(a1, o, 64);
    a2 += __shfl_xor(a2, o, 64);
  }
  if (sub == 0) {
    float dn = dinv[n];
    a0 = a0 * dn * m0 + R[n * 4 + 0];
    a1 = a1 * dn * m1 + R[n * 4 + 1];
    a2 = a2 * dn * m2 + R[n * 4 + 2];
    if (final_out) {
      float sm = (a0 + a1 + a2) * (1.f / 3.f);
      y[n] = 1.f / (1.f + expf(-sm));
    } else {
      out4[n * 4 + 0] = a0 * dn;
      out4[n * 4 + 1] = a1 * dn;
      out4[n * 4 + 2] = a2 * dn;
      out4[n * 4 + 3] = 0.f;
    }
  }
}

extern "C" void kernel_launch(void* const* d_in, const int* in_sizes, int n_in,
                              void* d_out, int out_size, void* d_ws, size_t ws_size,
                              hipStream_t stream) {
  const float* x   = (const float*)d_in[0];
  const int*   ei  = (const int*)d_in[1];
  const float* ea  = (const float*)d_in[2];
  // d_in[3] = batch (unused)
  const float* w1i = (const float*)d_in[4];
  const float* w1  = (const float*)d_in[5];
  const float* w1r = (const float*)d_in[6];
  const float* b1  = (const float*)d_in[7];
  const float* bng = (const float*)d_in[8];
  const float* bnb = (const float*)d_in[9];
  const float* w2i = (const float*)d_in[10];
  const float* w2  = (const float*)d_in[11];
  const float* w2r = (const float*)d_in[12];
  const float* b2  = (const float*)d_in[13];
  float* y = (float*)d_out;

  const int* row = ei;
  const int* col = ei + N_EDGES;

  char* ws = (char*)d_ws;
  size_t off = 0;
  auto alloc = [&](size_t bytes) -> char* {
    char* p = ws + off;
    off += (bytes + 255) & ~(size_t)255;
    return p;
  };
  u32*    gcur   = (u32*)alloc((size_t)NBUCK * 8 * 4);
  int*    offs   = (int*)alloc((size_t)(N_NODES + 1) * 4);
  float*  dinv   = (float*)alloc((size_t)N_NODES * 4);
  u16*    zx     = (u16*)alloc((size_t)N_NODES * 2);
  double* stats  = (double*)alloc(32 * 8);
  float*  bnsc   = (float*)alloc(16 * 4);
  float*  bnsh   = (float*)alloc(16 * 4);
  int2*   bucketed = (int2*)alloc((size_t)NBUCK * CAP * 8);
  u32*    csr    = (u32*)alloc((size_t)N_EDGES * 4);
  u16*    tA     = (u16*)alloc((size_t)N_NODES * FDIM * 2);
  u16*    tB     = (u16*)alloc((size_t)N_NODES * FDIM * 2);
  float*  hbuf   = (float*)alloc((size_t)N_NODES * NH * 4);
  float*  P2     = (float*)alloc((size_t)N_NODES * 4 * 4);
  float*  Q2     = (float*)alloc((size_t)N_NODES * 4 * 4);
  float*  R2     = (float*)alloc((size_t)N_NODES * 4 * 4);
  (void)ws_size; (void)in_sizes; (void)n_in; (void)out_size;

  hipMemsetAsync(gcur, 0, (size_t)NBUCK * 8 * 4, stream);
  hipMemsetAsync(stats, 0, 32 * 8, stream);

  bucket_scatter_kernel<<<NBLK1, 1024, 0, stream>>>(row, col, ea, gcur, bucketed);
  node_offs_csr_kernel<<<NBUCK, 1024, 0, stream>>>(bucketed, gcur, x, offs, dinv, zx, csr);

  const int NPB32 = 12500;  // N_NODES*32/256 exactly (32-lane groups)
  // conv1 layer 1 (rank-1 collapse): merged scalar prop + dense epilogue -> tA
  sprop_mid_kernel<<<NPB32, 256, 0, stream>>>(csr, offs, zx, dinv, x, w1i, w1r, b1, w1, tA);
  // conv1 layers 2-4: combined 3-stack propagation; 6250 blocks = 4 nodes/wave
  conv1_prop_kernel<<<6250, 256, 0, stream>>>(tA, tB, nullptr, csr, offs, dinv, x, w1r, b1, w1, 1);
  conv1_prop_kernel<<<6250, 256, 0, stream>>>(tB, tA, nullptr, csr, offs, dinv, x, w1r, b1, w1, 1);
  conv1_prop_kernel<<<6250, 256, 0, stream>>>(tA, nullptr, hbuf, csr, offs, dinv, x, w1r, b1, w1, 0);

  bn_stats_kernel<<<(N_NODES + 255) / 256, 256, 0, stream>>>(hbuf, stats);
  bn_final_kernel<<<1, 64, 0, stream>>>(stats, bng, bnb, bnsc, bnsh);
  conv2_init_kernel<<<(N_NODES + 255) / 256, 256, 0, stream>>>(
      hbuf, bnsc, bnsh, dinv, w2i, w2r, b2, P2, R2);

  conv2_prop_kernel<<<NPB32, 256, 0, stream>>>(P2, Q2, nullptr, csr, offs, dinv, R2, w2, 0, 0);
  conv2_prop_kernel<<<NPB32, 256, 0, stream>>>(Q2, P2, nullptr, csr, offs, dinv, R2, w2, 1, 0);
  conv2_prop_kernel<<<NPB32, 256, 0, stream>>>(P2, Q2, nullptr, csr, offs, dinv, R2, w2, 1, 0);
  conv2_prop_kernel<<<NPB32, 256, 0, stream>>>(Q2, P2, y, csr, offs, dinv, R2, w2, 1, 1);
}

// Round 10
// 468.136 us; speedup vs baseline: 1.0633x; 1.0633x over previous
//
#include <hip/hip_runtime.h>
#include <math.h>

#define N_NODES 100000
#define N_EDGES 3200000
#define KH 48            // K*H active channels
#define FDIM 64          // padded feature row stride (128 B, line-aligned)
#define NH 16            // H
#define BN_EPS 1e-5f
#define NBUCK 196        // ceil(100000/512) buckets of 512 nodes
#define BSHIFT 9
#define BMASK 511
#define EPB 8192         // edges per block in bucket scatter (391 blocks -> all CUs)
#define NBLK1 391        // ceil(N_EDGES/EPB)
#define CAP 18432        // fixed bucket capacity: mean 16327 + 16 sigma
#define FIX 16777216.0f  // 2^24 fixed point for degree sums

typedef unsigned long long u64;
typedef unsigned int u32;
typedef unsigned short u16;

__device__ __forceinline__ u16 f2bf(float f) {
  u32 b = __float_as_uint(f);
  b += 0x7FFFu + ((b >> 16) & 1u);   // RNE
  return (u16)(b >> 16);
}
__device__ __forceinline__ float bf2f(u32 s) {
  return __uint_as_float(s << 16);
}
__device__ __forceinline__ u32 rfl(u32 v) {
  return (u32)__builtin_amdgcn_readfirstlane((int)v);
}

// ---------------- K1: scatter edges into FIXED-CAPACITY buckets -------------
__global__ __launch_bounds__(1024) void bucket_scatter_kernel(
    const int* __restrict__ row, const int* __restrict__ col,
    const float* __restrict__ ea, u32* __restrict__ gcur,
    int2* __restrict__ bucketed) {
  __shared__ u32 bins[NBUCK];
  __shared__ u32 base[NBUCK];
  __shared__ u16 rnk[EPB];
  for (int t = threadIdx.x; t < NBUCK; t += 1024) bins[t] = 0;
  __syncthreads();
  int eb = blockIdx.x * EPB;
  for (int it = 0; it < EPB / 1024; ++it) {
    int i = it * 1024 + threadIdx.x;
    int e = eb + i;
    if (e < N_EDGES) rnk[i] = (u16)atomicAdd(&bins[col[e] >> BSHIFT], 1u);
  }
  __syncthreads();
  for (int t = threadIdx.x; t < NBUCK; t += 1024) {
    u32 c = bins[t];
    if (c) base[t] = (u32)t * CAP + atomicAdd(&gcur[t * 8], c);
  }
  __syncthreads();
  for (int it = 0; it < EPB / 1024; ++it) {
    int i = it * 1024 + threadIdx.x;
    int e = eb + i;
    if (e < N_EDGES) {
      int c = col[e];
      int bkt = c >> BSHIFT, cl = c & BMASK;
      u32 pos = base[bkt] + (u32)rnk[i];
      bucketed[pos] = make_int2((cl << 17) | row[e], __float_as_int(ea[e]));
    }
  }
}

// ---------------- P2: FUSED per-bucket offs/dinv/zx + csr fill --------------
__global__ __launch_bounds__(1024) void node_offs_csr_kernel(
    const int2* __restrict__ bucketed, const u32* __restrict__ gcur,
    const float* __restrict__ x,
    int* __restrict__ offs, float* __restrict__ dinv, u16* __restrict__ zx,
    u32* __restrict__ csr) {
  __shared__ u32 cnt[512];
  __shared__ u32 degf[512];
  __shared__ u32 cur[512];
  __shared__ u32 red[256];
  __shared__ u32 shmeta[2];   // [0]=bstart, [1]=fill
  int t = threadIdx.x;
  int b = blockIdx.x;
  if (t < 512) { cnt[t] = 0; degf[t] = 0; }
  if (t < 256) red[t] = (t < b) ? gcur[t * 8] : 0;   // NBUCK<256
  __syncthreads();
  for (int d = 128; d; d >>= 1) {
    if (t < d) red[t] += red[t + d];
    __syncthreads();
  }
  if (t == 0) { shmeta[0] = red[0]; shmeta[1] = gcur[b * 8]; }
  __syncthreads();
  u32 bst = shmeta[0], fill = shmeta[1];
  u32 s_pad = (u32)b * CAP;
  for (u32 i = t; i < fill; i += 1024) {
    int2 v = bucketed[s_pad + i];
    int cl = (v.x >> 17) & BMASK;
    atomicAdd(&cnt[cl], 1u);
    atomicAdd(&degf[cl], (u32)(__int_as_float(v.y) * FIX));
  }
  __syncthreads();
  u32 v0 = (t < 512) ? cnt[t] : 0;
  for (int d = 1; d < 512; d <<= 1) {
    u32 u = (t < 512 && t >= d) ? cnt[t - d] : 0;
    __syncthreads();
    if (t < 512) cnt[t] += u;
    __syncthreads();
  }
  int n = b * 512 + t;
  if (t < 512) {
    if (n < N_NODES) {
      u32 off0 = bst + cnt[t] - v0;   // exclusive, compact
      offs[n] = (int)off0;
      cur[t] = off0;
      float dg = (float)degf[t] * (1.0f / FIX);
      float dv = dg > 0.f ? rsqrtf(fmaxf(dg, 1e-12f)) : 0.f;
      dinv[n] = dv;
      zx[n] = f2bf(x[n] * dv);
    } else {
      cur[t] = 0;
    }
  }
  if (b == 0 && t == 0) offs[N_NODES] = N_EDGES;
  __syncthreads();
  for (u32 i = t; i < fill; i += 1024) {
    int2 v = bucketed[s_pad + i];
    int cl = (v.x >> 17) & BMASK;
    u32 r = (u32)(v.x & 0x1FFFF);
    u16 w = f2bf(__int_as_float(v.y));   // ea >= 0 -> sign bit 0, w < 0x8000
    u32 pos = atomicAdd(&cur[cl], 1u);
    csr[pos] = (r << 15) | (u32)w;
  }
}

// ---------------- layer-1: scalar prop + epilogue + transform (merged) ------
// 16-lane groups, 2-deep load-pair unroll: both csr loads issue before either
// zx gather -> halves the exposed (csr -> gather) serial latency chain.
__global__ __launch_bounds__(256) void sprop_mid_kernel(
    const u32* __restrict__ csr, const int* __restrict__ offs,
    const u16* __restrict__ zx, const float* __restrict__ dinv,
    const float* __restrict__ x,
    const float* __restrict__ w1i, const float* __restrict__ w1r,
    const float* __restrict__ b1, const float* __restrict__ w1,
    u16* __restrict__ tout) {
  int t = blockIdx.x * 256 + threadIdx.x;
  int n = t >> 4, c = t & 15;
  float a = 0.f;
  int s = offs[n], e = offs[n + 1];
  int i = s + c;
  for (; i + 16 < e; i += 32) {
    u32 e0 = csr[i];
    u32 e1 = csr[i + 16];
    float z0 = bf2f((u32)zx[e0 >> 15]);
    float z1 = bf2f((u32)zx[e1 >> 15]);
    a += bf2f(e0 & 0x7FFFu) * z0 + bf2f(e1 & 0x7FFFu) * z1;
  }
  if (i < e) {
    u32 e0 = csr[i];
    a += bf2f(e0 & 0x7FFFu) * bf2f((u32)zx[e0 >> 15]);
  }
#pragma unroll
  for (int o = 8; o; o >>= 1) a += __shfl_xor(a, o, 64);
  float dn = dinv[n];
  float sn = a * dn;
  float xn = x[n];
  int base = (threadIdx.x & 63) & 48;
#pragma unroll
  for (int k = 0; k < 3; ++k) {
    float u = fmaxf(sn * w1i[k * 16 + c] + xn * w1r[k * 16 + c] + b1[k * 16 + c], 0.f);
    float tf = 0.f;
#pragma unroll
    for (int f = 0; f < 16; ++f) tf += __shfl(u, base + f, 64) * w1[k * 256 + f * 16 + c];
    tout[(size_t)n * FDIM + k * 16 + c] = f2bf(tf * dn);
  }
}

// ---------------- conv1 propagate, all 3 stacks combined --------------------
// wave per node, lane = channel, 48 active; rows 128 B line-aligned.
// Scalar-path csr (readfirstlane -> SALU unpack, SGPR gather bases).
// [R4 form — 61.4 us, at 93% of the random-line fetch BW floor:
//  163 MB/dispatch at ~2.87 TB/s measured random-gather ceiling.]
__global__ __launch_bounds__(256) void conv1_prop_kernel(
    const u16* __restrict__ tin, u16* __restrict__ tout, float* __restrict__ hbuf,
    const u32* __restrict__ csr, const int* __restrict__ offs,
    const float* __restrict__ dinv, const float* __restrict__ x,
    const float* __restrict__ w1r, const float* __restrict__ b1,
    const float* __restrict__ w1, int do_t) {
  int lane = threadIdx.x & 63;
  int wid = (blockIdx.x * blockDim.x + threadIdx.x) >> 6;
  int nw = (gridDim.x * blockDim.x) >> 6;
  int c = lane;
  bool act = c < KH;
  float rb = act ? w1r[c] : 0.f;
  float bb = act ? b1[c] : 0.f;
  float wreg[16];
  if (do_t) {
    int k = c >> 4, o = c & 15;
    if (act) {
#pragma unroll
      for (int f = 0; f < 16; ++f) wreg[f] = w1[k * 256 + f * 16 + o];
    } else {
#pragma unroll
      for (int f = 0; f < 16; ++f) wreg[f] = 0.f;
    }
  }
  for (int n = wid; n < N_NODES; n += nw) {
    int nu = __builtin_amdgcn_readfirstlane(n);
    int s = __builtin_amdgcn_readfirstlane(offs[nu]);
    int e = __builtin_amdgcn_readfirstlane(offs[nu + 1]);
    float acc = 0.f;
    int i = s;
    for (; i + 16 <= e; i += 16) {
      u32 e0 = rfl(csr[i]);
      u32 e1 = rfl(csr[i + 1]);
      u32 e2 = rfl(csr[i + 2]);
      u32 e3 = rfl(csr[i + 3]);
      u32 e4 = rfl(csr[i + 4]);
      u32 e5 = rfl(csr[i + 5]);
      u32 e6 = rfl(csr[i + 6]);
      u32 e7 = rfl(csr[i + 7]);
      u32 e8 = rfl(csr[i + 8]);
      u32 e9 = rfl(csr[i + 9]);
      u32 ea0 = rfl(csr[i + 10]);
      u32 eb0 = rfl(csr[i + 11]);
      u32 ec0 = rfl(csr[i + 12]);
      u32 ed0 = rfl(csr[i + 13]);
      u32 ee0 = rfl(csr[i + 14]);
      u32 ef0 = rfl(csr[i + 15]);
      float v0 = bf2f((u32)tin[(e0 >> 15) * FDIM + c]);
      float v1 = bf2f((u32)tin[(e1 >> 15) * FDIM + c]);
      float v2 = bf2f((u32)tin[(e2 >> 15) * FDIM + c]);
      float v3 = bf2f((u32)tin[(e3 >> 15) * FDIM + c]);
      float v4 = bf2f((u32)tin[(e4 >> 15) * FDIM + c]);
      float v5 = bf2f((u32)tin[(e5 >> 15) * FDIM + c]);
      float v6 = bf2f((u32)tin[(e6 >> 15) * FDIM + c]);
      float v7 = bf2f((u32)tin[(e7 >> 15) * FDIM + c]);
      float v8 = bf2f((u32)tin[(e8 >> 15) * FDIM + c]);
      float v9 = bf2f((u32)tin[(e9 >> 15) * FDIM + c]);
      float va = bf2f((u32)tin[(ea0 >> 15) * FDIM + c]);
      float vb = bf2f((u32)tin[(eb0 >> 15) * FDIM + c]);
      float vc = bf2f((u32)tin[(ec0 >> 15) * FDIM + c]);
      float vd = bf2f((u32)tin[(ed0 >> 15) * FDIM + c]);
      float ve = bf2f((u32)tin[(ee0 >> 15) * FDIM + c]);
      float vf = bf2f((u32)tin[(ef0 >> 15) * FDIM + c]);
      acc += bf2f(e0 & 0x7FFFu) * v0 + bf2f(e1 & 0x7FFFu) * v1 +
             bf2f(e2 & 0x7FFFu) * v2 + bf2f(e3 & 0x7FFFu) * v3 +
             bf2f(e4 & 0x7FFFu) * v4 + bf2f(e5 & 0x7FFFu) * v5 +
             bf2f(e6 & 0x7FFFu) * v6 + bf2f(e7 & 0x7FFFu) * v7 +
             bf2f(e8 & 0x7FFFu) * v8 + bf2f(e9 & 0x7FFFu) * v9 +
             bf2f(ea0 & 0x7FFFu) * va + bf2f(eb0 & 0x7FFFu) * vb +
             bf2f(ec0 & 0x7FFFu) * vc + bf2f(ed0 & 0x7FFFu) * vd +
             bf2f(ee0 & 0x7FFFu) * ve + bf2f(ef0 & 0x7FFFu) * vf;
    }
    for (; i + 4 <= e; i += 4) {
      u32 e0 = rfl(csr[i]);
      u32 e1 = rfl(csr[i + 1]);
      u32 e2 = rfl(csr[i + 2]);
      u32 e3 = rfl(csr[i + 3]);
      float v0 = bf2f((u32)tin[(e0 >> 15) * FDIM + c]);
      float v1 = bf2f((u32)tin[(e1 >> 15) * FDIM + c]);
      float v2 = bf2f((u32)tin[(e2 >> 15) * FDIM + c]);
      float v3 = bf2f((u32)tin[(e3 >> 15) * FDIM + c]);
      acc += bf2f(e0 & 0x7FFFu) * v0 + bf2f(e1 & 0x7FFFu) * v1 +
             bf2f(e2 & 0x7FFFu) * v2 + bf2f(e3 & 0x7FFFu) * v3;
    }
    for (; i < e; ++i) {
      u32 ee = rfl(csr[i]);
      acc += bf2f(ee & 0x7FFFu) * bf2f((u32)tin[(ee >> 15) * FDIM + c]);
    }
    float dn = dinv[nu];
    float u = fmaxf(acc * dn + x[nu] * rb + bb, 0.f);
    if (do_t) {
      float tf = 0.f;
      int base = c & 48;
#pragma unroll
      for (int f = 0; f < 16; ++f) tf += __shfl(u, base + f, 64) * wreg[f];
      if (act) tout[(size_t)nu * FDIM + c] = f2bf(tf * dn);
    } else {
      float m1v = __shfl(u, lane + 16, 64);
      float m2v = __shfl(u, lane + 32, 64);
      if (lane < NH) hbuf[(size_t)nu * NH + lane] = (u + m1v + m2v) * (1.f / 3.f);
    }
  }
}

// ---------------- BN stats over hbuf [N,16] ---------------------------------
__global__ __launch_bounds__(256) void bn_stats_kernel(
    const float* __restrict__ h, double* __restrict__ stats) {
  __shared__ float ssum[NH], ssq[NH];
  int tid = threadIdx.x;
  if (tid < NH) { ssum[tid] = 0.f; ssq[tid] = 0.f; }
  __syncthreads();
  int n = blockIdx.x * blockDim.x + tid;
  bool valid = n < N_NODES;
  const float4* p = (const float4*)(h + (size_t)(valid ? n : 0) * NH);
  float hv[NH];
#pragma unroll
  for (int q = 0; q < 4; ++q) {
    float4 v = valid ? p[q] : make_float4(0.f, 0.f, 0.f, 0.f);
    hv[q * 4 + 0] = v.x; hv[q * 4 + 1] = v.y; hv[q * 4 + 2] = v.z; hv[q * 4 + 3] = v.w;
  }
#pragma unroll
  for (int f = 0; f < NH; ++f) {
    float s = hv[f], q = hv[f] * hv[f];
    for (int o = 32; o; o >>= 1) { s += __shfl_xor(s, o, 64); q += __shfl_xor(q, o, 64); }
    if ((tid & 63) == 0) { atomicAdd(&ssum[f], s); atomicAdd(&ssq[f], q); }
  }
  __syncthreads();
  if (tid < NH) {
    atomicAdd(&stats[tid], (double)ssum[tid]);
    atomicAdd(&stats[NH + tid], (double)ssq[tid]);
  }
}

__global__ __launch_bounds__(64) void bn_final_kernel(
    const double* __restrict__ stats, const float* __restrict__ g,
    const float* __restrict__ b, float* __restrict__ sc, float* __restrict__ sh) {
  int f = threadIdx.x;
  if (f < NH) {
    double mu = stats[f] / (double)N_NODES;
    double var = stats[NH + f] / (double)N_NODES - mu * mu;
    float scale = g[f] * (float)(1.0 / sqrt(var + (double)BN_EPS));
    sc[f] = scale;
    sh[f] = b[f] - (float)mu * scale;
  }
}

// ---------------- conv2 init: BN-apply + relu + init/root dots --------------
__global__ __launch_bounds__(256) void conv2_init_kernel(
    const float* __restrict__ h, const float* __restrict__ sc, const float* __restrict__ sh,
    const float* __restrict__ dinv,
    const float* __restrict__ w2i, const float* __restrict__ w2r, const float* __restrict__ b2,
    float* __restrict__ P, float* __restrict__ R) {
  int n = blockIdx.x * blockDim.x + threadIdx.x;
  if (n >= N_NODES) return;
  float u[NH];
#pragma unroll
  for (int f = 0; f < NH; ++f) u[f] = fmaxf(h[(size_t)n * NH + f] * sc[f] + sh[f], 0.f);
  float dn = dinv[n];
#pragma unroll
  for (int k = 0; k < 3; ++k) {
    float r = b2[k], o = 0.f;
#pragma unroll
    for (int f = 0; f < NH; ++f) {
      r += u[f] * w2r[k * NH + f];
      o += u[f] * w2i[k * NH + f];
    }
    R[n * 4 + k] = r;
    P[n * 4 + k] = o * dn;
  }
  R[n * 4 + 3] = 0.f;
  P[n * 4 + 3] = 0.f;
}

// ---------------- conv2 propagate: 16-lane groups, 2-deep unroll ------------
// Both csr loads of the typical 2 iterations issue before either float4
// gather -> exposed latency ~ (csr + gather) instead of 2x(csr + gather).
__global__ __launch_bounds__(256) void conv2_prop_kernel(
    const float* __restrict__ in4, float* __restrict__ out4, float* __restrict__ y,
    const u32* __restrict__ csr, const int* __restrict__ offs,
    const float* __restrict__ dinv,
    const float* __restrict__ R, const float* __restrict__ w2,
    int scale_w2, int final_out) {
  int t = blockIdx.x * 256 + threadIdx.x;
  int n = t >> 4, sub = t & 15;
  float m0 = 1.f, m1 = 1.f, m2 = 1.f;
  if (scale_w2) { m0 = w2[0]; m1 = w2[1]; m2 = w2[2]; }
  int s = offs[n], e = offs[n + 1];
  float a0 = 0.f, a1 = 0.f, a2 = 0.f;
  int i = s + sub;
  for (; i + 16 < e; i += 32) {
    u32 e0 = csr[i];
    u32 e1 = csr[i + 16];
    const float4 v0 = *(const float4*)(in4 + (size_t)(e0 >> 15) * 4);
    const float4 v1 = *(const float4*)(in4 + (size_t)(e1 >> 15) * 4);
    float w0 = bf2f(e0 & 0x7FFFu);
    float w1v = bf2f(e1 & 0x7FFFu);
    a0 += w0 * v0.x + w1v * v1.x;
    a1 += w0 * v0.y + w1v * v1.y;
    a2 += w0 * v0.z + w1v * v1.z;
  }
  if (i < e) {
    u32 ee = csr[i];
    float w = bf2f(ee & 0x7FFFu);
    const float4 v = *(const float4*)(in4 + (size_t)(ee >> 15) * 4);
    a0 += w * v.x;
    a1 += w * v.y;
    a2 += w * v.z;
  }
#pragma unroll
  for (int o = 8; o; o >>= 1) {
    a0 += __shfl_xor(a0, o, 64);
    a1 += __shfl_xor(a1, o, 64);
    a2 += __shfl_xor(a2, o, 64);
  }
  if (sub == 0) {
    float dn = dinv[n];
    a0 = a0 * dn * m0 + R[n * 4 + 0];
    a1 = a1 * dn * m1 + R[n * 4 + 1];
    a2 = a2 * dn * m2 + R[n * 4 + 2];
    if (final_out) {
      float sm = (a0 + a1 + a2) * (1.f / 3.f);
      y[n] = 1.f / (1.f + expf(-sm));
    } else {
      out4[n * 4 + 0] = a0 * dn;
      out4[n * 4 + 1] = a1 * dn;
      out4[n * 4 + 2] = a2 * dn;
      out4[n * 4 + 3] = 0.f;
    }
  }
}

extern "C" void kernel_launch(void* const* d_in, const int* in_sizes, int n_in,
                              void* d_out, int out_size, void* d_ws, size_t ws_size,
                              hipStream_t stream) {
  const float* x   = (const float*)d_in[0];
  const int*   ei  = (const int*)d_in[1];
  const float* ea  = (const float*)d_in[2];
  // d_in[3] = batch (unused)
  const float* w1i = (const float*)d_in[4];
  const float* w1  = (const float*)d_in[5];
  const float* w1r = (const float*)d_in[6];
  const float* b1  = (const float*)d_in[7];
  const float* bng = (const float*)d_in[8];
  const float* bnb = (const float*)d_in[9];
  const float* w2i = (const float*)d_in[10];
  const float* w2  = (const float*)d_in[11];
  const float* w2r = (const float*)d_in[12];
  const float* b2  = (const float*)d_in[13];
  float* y = (float*)d_out;

  const int* row = ei;
  const int* col = ei + N_EDGES;

  char* ws = (char*)d_ws;
  size_t off = 0;
  auto alloc = [&](size_t bytes) -> char* {
    char* p = ws + off;
    off += (bytes + 255) & ~(size_t)255;
    return p;
  };
  u32*    gcur   = (u32*)alloc((size_t)NBUCK * 8 * 4);
  int*    offs   = (int*)alloc((size_t)(N_NODES + 1) * 4);
  float*  dinv   = (float*)alloc((size_t)N_NODES * 4);
  u16*    zx     = (u16*)alloc((size_t)N_NODES * 2);
  double* stats  = (double*)alloc(32 * 8);
  float*  bnsc   = (float*)alloc(16 * 4);
  float*  bnsh   = (float*)alloc(16 * 4);
  int2*   bucketed = (int2*)alloc((size_t)NBUCK * CAP * 8);
  u32*    csr    = (u32*)alloc((size_t)N_EDGES * 4);
  u16*    tA     = (u16*)alloc((size_t)N_NODES * FDIM * 2);
  u16*    tB     = (u16*)alloc((size_t)N_NODES * FDIM * 2);
  float*  hbuf   = (float*)alloc((size_t)N_NODES * NH * 4);
  float*  P2     = (float*)alloc((size_t)N_NODES * 4 * 4);
  float*  Q2     = (float*)alloc((size_t)N_NODES * 4 * 4);
  float*  R2     = (float*)alloc((size_t)N_NODES * 4 * 4);
  (void)ws_size; (void)in_sizes; (void)n_in; (void)out_size;

  hipMemsetAsync(gcur, 0, (size_t)NBUCK * 8 * 4, stream);
  hipMemsetAsync(stats, 0, 32 * 8, stream);

  bucket_scatter_kernel<<<NBLK1, 1024, 0, stream>>>(row, col, ea, gcur, bucketed);
  node_offs_csr_kernel<<<NBUCK, 1024, 0, stream>>>(bucketed, gcur, x, offs, dinv, zx, csr);

  const int NPB = 6250;  // N_NODES*16/256 exactly
  // conv1 layer 1 (rank-1 collapse): merged scalar prop + dense epilogue -> tA
  sprop_mid_kernel<<<NPB, 256, 0, stream>>>(csr, offs, zx, dinv, x, w1i, w1r, b1, w1, tA);
  // conv1 layers 2-4: combined 3-stack propagation; 6250 blocks = 4 nodes/wave
  conv1_prop_kernel<<<6250, 256, 0, stream>>>(tA, tB, nullptr, csr, offs, dinv, x, w1r, b1, w1, 1);
  conv1_prop_kernel<<<6250, 256, 0, stream>>>(tB, tA, nullptr, csr, offs, dinv, x, w1r, b1, w1, 1);
  conv1_prop_kernel<<<6250, 256, 0, stream>>>(tA, nullptr, hbuf, csr, offs, dinv, x, w1r, b1, w1, 0);

  bn_stats_kernel<<<(N_NODES + 255) / 256, 256, 0, stream>>>(hbuf, stats);
  bn_final_kernel<<<1, 64, 0, stream>>>(stats, bng, bnb, bnsc, bnsh);
  conv2_init_kernel<<<(N_NODES + 255) / 256, 256, 0, stream>>>(
      hbuf, bnsc, bnsh, dinv, w2i, w2r, b2, P2, R2);

  conv2_prop_kernel<<<NPB, 256, 0, stream>>>(P2, Q2, nullptr, csr, offs, dinv, R2, w2, 0, 0);
  conv2_prop_kernel<<<NPB, 256, 0, stream>>>(Q2, P2, nullptr, csr, offs, dinv, R2, w2, 1, 0);
  conv2_prop_kernel<<<NPB, 256, 0, stream>>>(P2, Q2, nullptr, csr, offs, dinv, R2, w2, 1, 0);
  conv2_prop_kernel<<<NPB, 256, 0, stream>>>(Q2, P2, y, csr, offs, dinv, R2, w2, 1, 1);
}